// Round 3
// baseline (6600.792 us; speedup 1.0000x reference)
//
#include <hip/hip_runtime.h>

#define B_   32
#define NP_  192
#define C_   128
#define NS_  36
#define MID_ 64
#define FCH_ 128
#define RH_  10
#define RW_  25
#define FH_  40
#define FW_  100
#define L_   250
#define NR_  (B_*NP_)
#define EPS_ 1e-5f

// ---------------------------------------------------------------------------
// K1 (fused): 3x level conv9+BN+ReLU -> catconv9+BN+ReLU -> fc+LN+ReLU.
// One block per ROI, 256 threads. All intermediates in LDS. roi -> d_out.
// ---------------------------------------------------------------------------
__global__ __launch_bounds__(256) void k_roi(
    const float* __restrict__ rf0, const float* __restrict__ rf1, const float* __restrict__ rf2,
    const float* __restrict__ cw, const float* __restrict__ cg, const float* __restrict__ cb,
    const float* __restrict__ cm, const float* __restrict__ cv,
    const float* __restrict__ ww, const float* __restrict__ wg, const float* __restrict__ wb,
    const float* __restrict__ wm, const float* __restrict__ wvv,
    const float* __restrict__ fcw, const float* __restrict__ fcb,
    const float* __restrict__ lng, const float* __restrict__ lnb,
    float* __restrict__ roi)
{
  int n = blockIdx.x, tid = threadIdx.x;
  __shared__ float bufA[C_ * NS_];    // level-conv input, later catconv output (fc input)
  __shared__ float cs[192 * NS_];     // concatenated level-conv outputs
  __shared__ float hpart[256];
  __shared__ float hs[FCH_];

  // ---- stage 1: three per-level conv9 + BN + ReLU into cs ----
  for (int lev = 0; lev < 3; lev++) {
    const float* x = (lev == 0 ? rf0 : (lev == 1 ? rf1 : rf2)) + (size_t)n * (C_ * NS_);
    for (int i = tid; i < C_ * NS_ / 4; i += 256)
      reinterpret_cast<float4*>(bufA)[i] = reinterpret_cast<const float4*>(x)[i];
    __syncthreads();

    int o = tid & 63, sg = tid >> 6, s0 = sg * 9;
    int oc = lev * MID_ + o;
    float scale = cg[oc] * rsqrtf(cv[oc] + EPS_);
    float shift = cb[oc] - cm[oc] * scale;

    float acc[9];
    #pragma unroll
    for (int j = 0; j < 9; j++) acc[j] = 0.f;

    const float* wp = cw + (size_t)(oc * C_) * 9;
    for (int c = 0; c < C_; c++) {
      float xr[17];
      #pragma unroll
      for (int j = 0; j < 17; j++) {
        int p = s0 - 4 + j;
        xr[j] = ((unsigned)p < (unsigned)NS_) ? bufA[c * NS_ + p] : 0.f;
      }
      #pragma unroll
      for (int k = 0; k < 9; k++) {
        float wv = wp[c * 9 + k];
        #pragma unroll
        for (int j = 0; j < 9; j++) acc[j] = fmaf(wv, xr[j + k], acc[j]);
      }
    }
    #pragma unroll
    for (int j = 0; j < 9; j++)
      cs[oc * NS_ + s0 + j] = fmaxf(fmaf(scale, acc[j], shift), 0.f);
    __syncthreads();   // protect bufA before next level's load / catconv's write
  }

  // ---- stage 2: catconv9 + BN + ReLU, output into bufA ----
  {
    int o = tid & 127, sg = tid >> 7, s0 = sg * 18;
    float scale = wg[o] * rsqrtf(wvv[o] + EPS_);
    float shift = wb[o] - wm[o] * scale;
    float acc[18];
    #pragma unroll
    for (int j = 0; j < 18; j++) acc[j] = 0.f;
    const float* wp = ww + (size_t)(o * 192) * 9;
    for (int c = 0; c < 192; c++) {
      float xr[26];
      #pragma unroll
      for (int j = 0; j < 26; j++) {
        int p = s0 - 4 + j;
        xr[j] = ((unsigned)p < (unsigned)NS_) ? cs[c * NS_ + p] : 0.f;
      }
      #pragma unroll
      for (int k = 0; k < 9; k++) {
        float w = wp[c * 9 + k];
        #pragma unroll
        for (int j = 0; j < 18; j++) acc[j] = fmaf(w, xr[j + k], acc[j]);
      }
    }
    #pragma unroll
    for (int j = 0; j < 18; j++)
      bufA[o * NS_ + s0 + j] = fmaxf(fmaf(scale, acc[j], shift), 0.f);
  }
  __syncthreads();

  // ---- stage 3: fc (h[f] = sum_i bufA[i] * fc_w[f,i], i = c*36+s) ----
  {
    int f = tid & 127, half = tid >> 7;
    int base = half * 2304;
    const float4* wp4 = reinterpret_cast<const float4*>(fcw + (size_t)f * 4608 + base);
    const float* ob = bufA + base;
    float a = 0.f;
    for (int i = 0; i < 576; i++) {
      float4 u = wp4[i];
      a = fmaf(u.x, ob[4 * i + 0], a);
      a = fmaf(u.y, ob[4 * i + 1], a);
      a = fmaf(u.z, ob[4 * i + 2], a);
      a = fmaf(u.w, ob[4 * i + 3], a);
    }
    hpart[tid] = a;
  }
  __syncthreads();
  if (tid < FCH_) hs[tid] = hpart[tid] + hpart[tid + 128] + fcb[tid];
  __syncthreads();

  // ---- stage 4: LayerNorm + ReLU ----
  if (tid < FCH_) {
    float sum = 0.f, sumsq = 0.f;
    for (int i = 0; i < FCH_; i++) { float h = hs[i]; sum += h; sumsq = fmaf(h, h, sumsq); }
    float mu  = sum * (1.f / FCH_);
    float var = sumsq * (1.f / FCH_) - mu * mu;
    float rr  = rsqrtf(var + EPS_);
    float v   = fmaxf((hs[tid] - mu) * rr * lng[tid] + lnb[tid], 0.f);
    roi[(size_t)n * FCH_ + tid] = v;
  }
}

// ---------------------------------------------------------------------------
// K2: key/val projections only at the 250 nearest-resize sample points.
// grid (250, B), block 128 (one thread per out channel).
// ---------------------------------------------------------------------------
__global__ __launch_bounds__(128) void k_kv(
    const float* __restrict__ fmap,
    const float* __restrict__ kw, const float* __restrict__ kg, const float* __restrict__ kbeta,
    const float* __restrict__ km, const float* __restrict__ kvv,
    const float* __restrict__ vw, const float* __restrict__ vb,
    float* __restrict__ kbuf, float* __restrict__ vbuf)
{
  int l = blockIdx.x, b = blockIdx.y, tid = threadIdx.x;
  int r = l / RW_, s = l % RW_;
  int pix = (r * FH_ / RH_) * FW_ + (s * FW_ / RW_);   // (4r, 4s)
  __shared__ float fs[C_];
  fs[tid] = fmap[((size_t)b * C_ + tid) * (FH_ * FW_) + pix];
  __syncthreads();

  int c = tid;
  const float4* kwp = reinterpret_cast<const float4*>(kw + (size_t)c * C_);
  const float4* vwp = reinterpret_cast<const float4*>(vw + (size_t)c * C_);
  float kk = 0.f, vv = 0.f;
  for (int i = 0; i < 32; i++) {
    float4 ku = kwp[i]; float4 vu = vwp[i];
    const float* fb = fs + i * 4;
    kk = fmaf(ku.x, fb[0], kk);  vv = fmaf(vu.x, fb[0], vv);
    kk = fmaf(ku.y, fb[1], kk);  vv = fmaf(vu.y, fb[1], vv);
    kk = fmaf(ku.z, fb[2], kk);  vv = fmaf(vu.z, fb[2], vv);
    kk = fmaf(ku.w, fb[3], kk);  vv = fmaf(vu.w, fb[3], vv);
  }
  float scale = kg[c] * rsqrtf(kvv[c] + EPS_);
  float shift = kbeta[c] - km[c] * scale;
  kbuf[((size_t)b * C_ + c) * L_ + l] = fmaxf(fmaf(scale, kk, shift), 0.f);
  vbuf[((size_t)b * L_ + l) * C_ + c] = vv + vb[c];
}

// ---------------------------------------------------------------------------
// K3: attention per (b, n).  grid NR, block 256.  In-place: out == roi buffer.
// ---------------------------------------------------------------------------
__global__ __launch_bounds__(256) void k_attn(
    const float* __restrict__ kbuf, const float* __restrict__ vbuf,
    const float* __restrict__ qw, const float* __restrict__ qb,
    const float* __restrict__ gw, const float* __restrict__ gb,
    float* __restrict__ out)
{
  int nglob = blockIdx.x;
  int b = nglob / NP_, np = nglob % NP_;
  int tid = threadIdx.x;
  __shared__ float qs[C_];
  __shared__ float ps[256];
  __shared__ float rbuf[8];

  float* rp = out + (size_t)nglob * C_;
  if (tid < C_) qs[tid] = fmaxf(fmaf(rp[tid], qw[np], qb[np]), 0.f);
  __syncthreads();

  float sc = -1e30f;
  if (tid < L_) {
    const float* kp = kbuf + (size_t)b * (C_ * L_) + tid;
    float a = 0.f;
    for (int c = 0; c < C_; c++) a = fmaf(qs[c], kp[c * L_], a);
    sc = a * 0.088388347648318447f;   // 1/sqrt(128)
  }
  // block max
  float m = sc;
  #pragma unroll
  for (int off = 32; off; off >>= 1) m = fmaxf(m, __shfl_xor(m, off, 64));
  if ((tid & 63) == 0) rbuf[tid >> 6] = m;
  __syncthreads();
  m = fmaxf(fmaxf(rbuf[0], rbuf[1]), fmaxf(rbuf[2], rbuf[3]));

  float e = (tid < L_) ? __expf(sc - m) : 0.f;
  ps[tid] = e;
  float s = e;
  #pragma unroll
  for (int off = 32; off; off >>= 1) s += __shfl_xor(s, off, 64);
  if ((tid & 63) == 0) rbuf[4 + (tid >> 6)] = s;
  __syncthreads();
  float S = rbuf[4] + rbuf[5] + rbuf[6] + rbuf[7];
  float inv = 1.f / S;

  if (tid < C_) {
    const float* vp = vbuf + (size_t)b * (L_ * C_) + tid;
    float a = 0.f;
    for (int l = 0; l < L_; l++) a = fmaf(ps[l], vp[l * C_], a);
    a *= inv;
    rp[tid] = rp[tid] + a * gw[np] + gb[np];   // in-place residual add
  }
}

// ---------------------------------------------------------------------------
extern "C" void kernel_launch(void* const* d_in, const int* in_sizes, int n_in,
                              void* d_out, int out_size, void* d_ws, size_t ws_size,
                              hipStream_t stream)
{
  const float* rf0    = (const float*)d_in[0];
  const float* rf1    = (const float*)d_in[1];
  const float* rf2    = (const float*)d_in[2];
  const float* fmap   = (const float*)d_in[3];
  const float* conv_w = (const float*)d_in[4];
  const float* conv_g = (const float*)d_in[5];
  const float* conv_b = (const float*)d_in[6];
  const float* conv_m = (const float*)d_in[7];
  const float* conv_v = (const float*)d_in[8];
  const float* cat_w  = (const float*)d_in[9];
  const float* cat_g  = (const float*)d_in[10];
  const float* cat_b  = (const float*)d_in[11];
  const float* cat_m  = (const float*)d_in[12];
  const float* cat_v  = (const float*)d_in[13];
  const float* fc_w   = (const float*)d_in[14];
  const float* fc_b   = (const float*)d_in[15];
  const float* ln_g   = (const float*)d_in[16];
  const float* ln_b   = (const float*)d_in[17];
  const float* key_w  = (const float*)d_in[18];
  const float* key_g  = (const float*)d_in[19];
  const float* key_be = (const float*)d_in[20];
  const float* key_m  = (const float*)d_in[21];
  const float* key_v  = (const float*)d_in[22];
  const float* q_w    = (const float*)d_in[23];
  const float* q_b    = (const float*)d_in[24];
  const float* val_w  = (const float*)d_in[25];
  const float* val_b  = (const float*)d_in[26];
  const float* gate_w = (const float*)d_in[27];
  const float* gate_b = (const float*)d_in[28];
  // d_in[29] = layer_index (int); with layer_index==2 the reference applies the
  // single cat_w conv after concatenation. Unused in the math.

  // roi lives in d_out (same size); ws holds only k/v: 8.2 MB.
  float* roi  = (float*)d_out;
  char*  ws   = (char*)d_ws;
  float* kbuf = (float*)ws;                                   // B*C*L*4   = 4.096 MB
  float* vbuf = (float*)(ws + (size_t)B_ * C_ * L_ * 4);      // B*L*C*4   = 4.096 MB

  k_kv<<<dim3(L_, B_), 128, 0, stream>>>(fmap, key_w, key_g, key_be, key_m, key_v,
                                         val_w, val_b, kbuf, vbuf);
  k_roi<<<dim3(NR_), 256, 0, stream>>>(rf0, rf1, rf2, conv_w, conv_g, conv_b,
                                       conv_m, conv_v, cat_w, cat_g, cat_b, cat_m,
                                       cat_v, fc_w, fc_b, ln_g, ln_b, roi);
  k_attn<<<dim3(NR_), 256, 0, stream>>>(kbuf, vbuf, q_w, q_b, gate_w, gate_b, roi);
}